// Round 13
// baseline (149.916 us; speedup 1.0000x reference)
//
#include <hip/hip_runtime.h>

// GAT 2-layer v12: independent-work fusion — {Wcast ∥ scatter} and
// {bucket_sort ∥ gemm1} as fat kernels. 6 dispatches total.
// fp16 rows + MFMA gemm + per-wave CSR gather agg (BW-bound floor).
// N=50000, E=800000 (+N self loops), H=4 heads, C=32, HC=128.

typedef float f32x4 __attribute__((ext_vector_type(4)));
typedef _Float16 f16x8 __attribute__((ext_vector_type(8)));
typedef _Float16 f16x2 __attribute__((ext_vector_type(2)));
typedef _Float16 halfT;

#define SCHUNK 2048
#define MAXNB 1024   // 64-node buckets; supports N <= 65536
#define BCAP 2048    // slots per bucket window (expected ~1088, 29-sigma margin)

// ---- device helpers --------------------------------------------------------
__device__ __forceinline__ void wcast_body(
    const float* __restrict__ W1, const float* __restrict__ W2,
    halfT* __restrict__ wf1, halfT* __restrict__ wf2, int blk) {
  int idx = blk * 256 + threadIdx.x;  // 0..32767
  const float* W = (idx < 16384) ? W1 : W2;
  halfT* wf = (idx < 16384) ? wf1 : wf2;
  int i = idx & 16383;
  int j = i & 7, lane = (i >> 3) & 63, ks = (i >> 9) & 3, nt = i >> 11;
  int k = ks * 32 + (lane >> 4) * 8 + j;
  int n = nt * 16 + (lane & 15);
  wf[i] = (halfT)W[k * 128 + n];
}

__device__ __forceinline__ void scatter_body(
    const int* __restrict__ src, const int* __restrict__ dst,
    int* __restrict__ bcur, unsigned* __restrict__ epack,
    int Etot, int E, int NB, int chunk) {
  __shared__ int h[MAXNB];
  __shared__ int cur[MAXNB];
  int t = threadIdx.x;
  int e0 = chunk * SCHUNK;
  int e1 = min(e0 + SCHUNK, Etot);
  for (int i = t; i < NB; i += 256) h[i] = 0;
  __syncthreads();
  for (int e = e0 + t; e < e1; e += 256) {
    int d = (e < E) ? dst[e] : (e - E);
    atomicAdd(&h[d >> 6], 1);
  }
  __syncthreads();
  for (int i = t; i < NB; i += 256) {
    int c = h[i];
    cur[i] = c ? atomicAdd(&bcur[i], c) : 0;  // bucket-local base
  }
  __syncthreads();
  for (int e = e0 + t; e < e1; e += 256) {
    int s = (e < E) ? src[e] : (e - E);
    int d = (e < E) ? dst[e] : (e - E);
    int b = d >> 6;
    int pos = atomicAdd(&cur[b], 1);
    if (pos < BCAP)  // overflow guard (never hit for this input)
      epack[(size_t)b * BCAP + pos] = ((unsigned)(d & 63) << 26) | (unsigned)s;
  }
}

// ---- D1: {W casts} ∥ {bucket-windowed scatter} -----------------------------
__global__ __launch_bounds__(256) void prep_scatter_kernel(
    const float* __restrict__ W1, const float* __restrict__ W2,
    halfT* __restrict__ wf1, halfT* __restrict__ wf2,
    const int* __restrict__ src, const int* __restrict__ dst,
    int* __restrict__ bcur, unsigned* __restrict__ epack,
    int Etot, int E, int NB) {
  if (blockIdx.x < 128)
    wcast_body(W1, W2, wf1, wf2, blockIdx.x);
  else
    scatter_body(src, dst, bcur, epack, Etot, E, NB, blockIdx.x - 128);
}

// ---- gemm body: 128 rows/block (2 tiles), optional fp32-A cast -------------
template <int CAST>
__device__ __forceinline__ void gemm_body(
    const float* __restrict__ Xf, const halfT* __restrict__ Xh,
    const halfT* __restrict__ Wf,
    const float* __restrict__ a_src, const float* __restrict__ a_dst,
    halfT* __restrict__ Hh, float* __restrict__ ssrc, float* __restrict__ sdst,
    int N, int bid) {
  __shared__ f16x8 wlds[2048];
  __shared__ float cst[4][16][134];
  int t = threadIdx.x;
  for (int i = t; i < 2048; i += 256) wlds[i] = ((const f16x8*)Wf)[i];
  __syncthreads();

  int w = t >> 6, lane = t & 63;

  for (int tile = 0; tile < 2; ++tile) {
    int growbase = bid * 128 + tile * 64 + w * 16;
    int arow = growbase + (lane & 15);
    if (arow > N - 1) arow = N - 1;  // clamp: no OOB reads

    f32x4 acc[8];
#pragma unroll
    for (int nt = 0; nt < 8; ++nt) acc[nt] = (f32x4){0.f, 0.f, 0.f, 0.f};

#pragma unroll
    for (int ks = 0; ks < 4; ++ks) {
      f16x8 af;
      if (CAST) {
        const f32x4* xr = (const f32x4*)(Xf + (size_t)arow * 128 + (lane >> 4) * 8);
        f32x4 a = xr[ks * 8];
        f32x4 b = xr[ks * 8 + 1];
        af[0] = (halfT)a.x; af[1] = (halfT)a.y; af[2] = (halfT)a.z; af[3] = (halfT)a.w;
        af[4] = (halfT)b.x; af[5] = (halfT)b.y; af[6] = (halfT)b.z; af[7] = (halfT)b.w;
      } else {
        const f16x8* xr = (const f16x8*)(Xh + (size_t)arow * 128 + (lane >> 4) * 8);
        af = xr[ks * 4];
      }
#pragma unroll
      for (int nt = 0; nt < 8; ++nt)
        acc[nt] = __builtin_amdgcn_mfma_f32_16x16x32_f16(
            af, wlds[(nt * 4 + ks) * 64 + lane], acc[nt], 0, 0, 0);
    }

#pragma unroll
    for (int nt = 0; nt < 8; ++nt)
#pragma unroll
      for (int j = 0; j < 4; ++j)
        cst[w][(lane >> 4) * 4 + j][nt * 16 + (lane & 15)] = acc[nt][j];
    __syncthreads();

    int r = lane >> 2, q = lane & 3;
    int grow = growbase + r;
    if (grow < N) {
      const float* cp = &cst[w][r][q * 32];
      const float* asp = a_src + q * 32;
      const float* adp = a_dst + q * 32;
      f16x8* hp = (f16x8*)(Hh + (size_t)grow * 128 + q * 32);
      float ss = 0.f, sd = 0.f;
#pragma unroll
      for (int g = 0; g < 4; ++g) {
        f16x8 hv;
#pragma unroll
        for (int jj = 0; jj < 8; ++jj) {
          float v = cp[g * 8 + jj];
          ss = fmaf(v, asp[g * 8 + jj], ss);
          sd = fmaf(v, adp[g * 8 + jj], sd);
          hv[jj] = (halfT)v;
        }
        hp[g] = hv;
      }
      ssrc[grow * 4 + q] = ss;
      sdst[grow * 4 + q] = sd;
    }
    __syncthreads();
  }
}

// ---- bucket_sort body ------------------------------------------------------
__device__ __forceinline__ void sort_body(
    const unsigned* __restrict__ epack, const int* __restrict__ bcur,
    int* __restrict__ csr_src, int2* __restrict__ rowinfo, int N, int b) {
  __shared__ int cnt[64];
  __shared__ int cur[64];
  __shared__ int cstart[64];
  int t = threadIdx.x;
  int wbase = b * BCAP;
  int ec = min(bcur[b], BCAP);
  if (t < 64) cnt[t] = 0;
  __syncthreads();
  for (int e = t; e < ec; e += 256)
    atomicAdd(&cnt[epack[wbase + e] >> 26], 1);
  __syncthreads();
  if (t == 0) {
    int run = wbase;
    for (int i = 0; i < 64; ++i) { cur[i] = run; cstart[i] = run; run += cnt[i]; }
  }
  __syncthreads();
  if (t < 64) {
    int gn = b * 64 + t;
    if (gn < N) rowinfo[gn] = make_int2(cstart[t], cnt[t]);
  }
  for (int e = t; e < ec; e += 256) {
    unsigned pk = epack[wbase + e];
    int pos = atomicAdd(&cur[pk >> 26], 1);
    csr_src[pos] = (int)(pk & 0x3FFFFFFu);
  }
}

// ---- D2: {bucket_sort} ∥ {gemm layer 1 (fp32-A cast)} ----------------------
__global__ __launch_bounds__(256) void sort_gemm_kernel(
    const unsigned* __restrict__ epack, const int* __restrict__ bcur,
    int* __restrict__ csr_src, int2* __restrict__ rowinfo,
    const float* __restrict__ Xf, const halfT* __restrict__ Wf,
    const float* __restrict__ a_src, const float* __restrict__ a_dst,
    halfT* __restrict__ Hh, float* __restrict__ ssrc, float* __restrict__ sdst,
    int N, int NB) {
  if (blockIdx.x < (unsigned)NB)
    sort_body(epack, bcur, csr_src, rowinfo, N, blockIdx.x);
  else
    gemm_body<1>(Xf, nullptr, Wf, a_src, a_dst, Hh, ssrc, sdst, N,
                 blockIdx.x - NB);
}

// ---- standalone gemm (layer 2, fp16 input) ---------------------------------
__global__ __launch_bounds__(256) void gemm_mfma_kernel(
    const halfT* __restrict__ Xh, const halfT* __restrict__ Wf,
    const float* __restrict__ a_src, const float* __restrict__ a_dst,
    halfT* __restrict__ Hh, float* __restrict__ ssrc, float* __restrict__ sdst,
    int N) {
  gemm_body<0>(nullptr, Xh, Wf, a_src, a_dst, Hh, ssrc, sdst, N, blockIdx.x);
}

// ---------------- fused aggregation: one wave per dst node, unroll-8 --------
template <int FINAL>
__global__ __launch_bounds__(256) void agg_kernel(
    const int2* __restrict__ rowinfo, const int* __restrict__ csr_src,
    const float* __restrict__ ssrc, const float* __restrict__ sdst,
    const halfT* __restrict__ Hin, const float* __restrict__ bias,
    const float* __restrict__ lw, const float* __restrict__ lb,
    float* __restrict__ out, int N) {
  __shared__ float4 pbuf[4][64];
  int wid = threadIdx.x >> 6;
  int n = blockIdx.x * 4 + wid;
  if (n >= N) return;
  int lane = threadIdx.x & 63;
  int head = lane >> 4;
  int2 ri = rowinfo[n];
  int base = ri.x, deg = ri.y;
  float4 sd = ((const float4*)sdst)[n];
  const float* pb = (const float*)&pbuf[wid][0];

  float z0 = 0.f, z1 = 0.f, z2 = 0.f, z3 = 0.f;
  float ax = 0.f, ay = 0.f;

  for (int c = 0; c < deg; c += 64) {
    int i = c + lane;
    int sreg = 0;
    if (i < deg) {
      sreg = csr_src[base + i];
      float4 ss = ((const float4*)ssrc)[sreg];
      float e0 = ss.x + sd.x, e1 = ss.y + sd.y;
      float e2 = ss.z + sd.z, e3 = ss.w + sd.w;
      e0 = e0 > 0.f ? e0 : 0.2f * e0;
      e1 = e1 > 0.f ? e1 : 0.2f * e1;
      e2 = e2 > 0.f ? e2 : 0.2f * e2;
      e3 = e3 > 0.f ? e3 : 0.2f * e3;
      float p0 = __expf(e0), p1 = __expf(e1);
      float p2 = __expf(e2), p3 = __expf(e3);
      z0 += p0; z1 += p1; z2 += p2; z3 += p3;
      pbuf[wid][lane] = make_float4(p0, p1, p2, p3);
    }
    int cl = min(64, deg - c);
    int k = 0;
    for (; k + 8 <= cl; k += 8) {
      int sA[8];
      f16x2 vA[8];
#pragma unroll
      for (int u = 0; u < 8; ++u) sA[u] = __shfl(sreg, k + u);
#pragma unroll
      for (int u = 0; u < 8; ++u)
        vA[u] = ((const f16x2*)(Hin + ((size_t)sA[u] << 7)))[lane];
#pragma unroll
      for (int u = 0; u < 8; ++u) {
        float q = pb[(k + u) * 4 + head];
        ax = fmaf(q, (float)vA[u][0], ax);
        ay = fmaf(q, (float)vA[u][1], ay);
      }
    }
    for (; k + 4 <= cl; k += 4) {
      int s0 = __shfl(sreg, k);
      int s1 = __shfl(sreg, k + 1);
      int s2 = __shfl(sreg, k + 2);
      int s3 = __shfl(sreg, k + 3);
      f16x2 v0 = ((const f16x2*)(Hin + ((size_t)s0 << 7)))[lane];
      f16x2 v1 = ((const f16x2*)(Hin + ((size_t)s1 << 7)))[lane];
      f16x2 v2 = ((const f16x2*)(Hin + ((size_t)s2 << 7)))[lane];
      f16x2 v3 = ((const f16x2*)(Hin + ((size_t)s3 << 7)))[lane];
      float q0 = pb[k * 4 + head];
      float q1 = pb[(k + 1) * 4 + head];
      float q2 = pb[(k + 2) * 4 + head];
      float q3 = pb[(k + 3) * 4 + head];
      ax = fmaf(q0, (float)v0[0], ax); ay = fmaf(q0, (float)v0[1], ay);
      ax = fmaf(q1, (float)v1[0], ax); ay = fmaf(q1, (float)v1[1], ay);
      ax = fmaf(q2, (float)v2[0], ax); ay = fmaf(q2, (float)v2[1], ay);
      ax = fmaf(q3, (float)v3[0], ax); ay = fmaf(q3, (float)v3[1], ay);
    }
    for (; k < cl; ++k) {
      int s0 = __shfl(sreg, k);
      f16x2 v0 = ((const f16x2*)(Hin + ((size_t)s0 << 7)))[lane];
      float q0 = pb[k * 4 + head];
      ax = fmaf(q0, (float)v0[0], ax); ay = fmaf(q0, (float)v0[1], ay);
    }
  }

#pragma unroll
  for (int off = 32; off; off >>= 1) {
    z0 += __shfl_xor(z0, off);
    z1 += __shfl_xor(z1, off);
    z2 += __shfl_xor(z2, off);
    z3 += __shfl_xor(z3, off);
  }
  float zz = (head == 0) ? z0 : (head == 1) ? z1 : (head == 2) ? z2 : z3;
  float rz = 1.f / (zz + 1e-16f);
  float2 bb = ((const float2*)bias)[lane];
  float ox = fmaxf(fmaf(ax, rz, bb.x), 0.f);
  float oy = fmaxf(fmaf(ay, rz, bb.y), 0.f);

  if (FINAL) {
    float2 ww = ((const float2*)lw)[lane];
    float v = ox * ww.x + oy * ww.y;
#pragma unroll
    for (int off = 32; off; off >>= 1) v += __shfl_down(v, off);
    if (lane == 0) out[n] = v + lb[0];
  } else {
    ((f16x2*)out)[(size_t)n * 64 + lane] = (f16x2){(halfT)ox, (halfT)oy};
  }
}

extern "C" void kernel_launch(void* const* d_in, const int* in_sizes, int n_in,
                              void* d_out, int out_size, void* d_ws, size_t ws_size,
                              hipStream_t stream) {
  const float* x   = (const float*)d_in[0];
  const int*   src = (const int*)d_in[1];
  const int*   dst = (const int*)d_in[2];
  const float* W1  = (const float*)d_in[3];
  const float* as1 = (const float*)d_in[4];
  const float* ad1 = (const float*)d_in[5];
  const float* b1  = (const float*)d_in[6];
  const float* W2  = (const float*)d_in[7];
  const float* as2 = (const float*)d_in[8];
  const float* ad2 = (const float*)d_in[9];
  const float* b2  = (const float*)d_in[10];
  const float* lw  = (const float*)d_in[11];
  const float* lb  = (const float*)d_in[12];

  int N = in_sizes[0] / 128;
  int E = in_sizes[1];
  int Etot = E + N;
  int NB = (N + 63) / 64;
  int nb128 = (N + 127) / 128;
  int Npad = nb128 * 128;

  char* w = (char*)d_ws;
  halfT* h16  = (halfT*)w; w += (size_t)Npad * 128 * 2;
  halfT* xb16 = (halfT*)w; w += (size_t)Npad * 128 * 2;
  halfT* wf1  = (halfT*)w; w += 16384 * 2;
  halfT* wf2  = (halfT*)w; w += 16384 * 2;
  float* ssrc = (float*)w; w += (size_t)N * 4 * 4;
  float* sdst = (float*)w; w += (size_t)N * 4 * 4;
  int* bcur   = (int*)w;   w += MAXNB * 4;
  int2* rowinfo = (int2*)w; w += (size_t)(N + 64) * 8;
  unsigned* epack = (unsigned*)w; w += (size_t)NB * BCAP * 4;
  int* csr_src = (int*)w;  w += (size_t)NB * BCAP * 4;

  int sc_grid  = (Etot + SCHUNK - 1) / SCHUNK;
  int agg_grid = (N + 3) / 4;

  // ---- D0: zero bucket cursors (tiny fill) ----
  hipMemsetAsync(bcur, 0, MAXNB * 4, stream);

  // ---- D1: {W1+W2 cast} ∥ {bucket-windowed scatter} ----
  prep_scatter_kernel<<<128 + sc_grid, 256, 0, stream>>>(
      W1, W2, wf1, wf2, src, dst, bcur, epack, Etot, E, NB);

  // ---- D2: {bucket counting sort} ∥ {gemm layer 1} ----
  sort_gemm_kernel<<<NB + nb128, 256, 0, stream>>>(
      epack, bcur, csr_src, rowinfo, x, wf1, as1, ad1, h16, ssrc, sdst, N, NB);

  // ---- D3: agg layer 1 ----
  agg_kernel<0><<<agg_grid, 256, 0, stream>>>(rowinfo, csr_src, ssrc, sdst, h16,
                                              b1, nullptr, nullptr, (float*)xb16, N);

  // ---- D4: gemm layer 2 ----
  gemm_mfma_kernel<<<nb128, 256, 0, stream>>>(xb16, wf2, as2, ad2,
                                              h16, ssrc, sdst, N);

  // ---- D5: agg layer 2 (fused final linear) ----
  agg_kernel<1><<<agg_grid, 256, 0, stream>>>(rowinfo, csr_src, ssrc, sdst, h16,
                                              b2, lw, lb, (float*)d_out, N);
}